// Round 5
// baseline (450.361 us; speedup 1.0000x reference)
//
#include <hip/hip_runtime.h>
#include <math.h>

#define CDIM 192
#define HWP 9216      // 96*96
#define WIMG 96
#define HIMG 96
#define BDIM 16

typedef float f32x4 __attribute__((ext_vector_type(4)));
typedef short bf16x8 __attribute__((ext_vector_type(8)));

__device__ __forceinline__ ushort f2bf(float f) {
    uint u = __builtin_bit_cast(uint, f);
    u += 0x7FFFu + ((u >> 16) & 1);           // round-to-nearest-even
    return (ushort)(u >> 16);
}
__device__ __forceinline__ float bf2f(ushort h) {
    return __builtin_bit_cast(float, (uint)h << 16);
}

// ---------------- prep: bake W (o-major [192][192] fp32) into MFMA B-fragment order ----------------
// Wf[((ks*12 + nf)*64 + l)*8 + i] = bf16( W[o=nf*16+(l&15)][c = ks*32 + (l>>4)*8 + i] )
// The (g,i)->k mapping is applied identically on the A-side gather, so any hw k-permutation cancels.
__global__ void prep_wfrag_kernel(const float* __restrict__ Wx, const float* __restrict__ Wp,
                                  ushort* __restrict__ WxF, ushort* __restrict__ WpF) {
    int t = blockIdx.x * 256 + threadIdx.x;    // 0 .. 9215
    int m = t / 4608;
    int r = t % 4608;                          // ks*768 + nf*64 + l
    int ks = r / 768, nf = (r / 64) % 12, l = r % 64;
    const float* W = m ? Wp : Wx;
    ushort* F = m ? WpF : WxF;
    int o = nf * 16 + (l & 15);
    int c0 = ks * 32 + (l >> 4) * 8;
    float4 a = *(const float4*)&W[o * CDIM + c0];
    float4 b = *(const float4*)&W[o * CDIM + c0 + 4];
    ushort* dst = F + (size_t)r * 8;
    dst[0] = f2bf(a.x); dst[1] = f2bf(a.y); dst[2] = f2bf(a.z); dst[3] = f2bf(a.w);
    dst[4] = f2bf(b.x); dst[5] = f2bf(b.y); dst[6] = f2bf(b.z); dst[7] = f2bf(b.w);
}

// ---------------- MFMA conv1x1 (no LDS): out[o][p] = sum_c W[o][c] in[c][p] + bias[o] ----------------
// Block: 64 pixels x 192 out-ch, 4 independent waves; wave w owns pixels [p0+16w, +16).
// A-frag gathered per lane straight from global: lane l: pixel pA = p0+w*16+(l&15),
//   c = ks*32 + (l>>4)*8 + i. Lanes 0..15 read 64 consecutive bytes (fp32) per (ks,i) -> coalesced;
//   the block's 4 waves + 4 c-groups cover whole cache lines. Each element read exactly once.
// B-frag: 16B load from pre-baked Wf (L2-hot). D: row=pixel=(l>>4)*4+reg, col=o=(l&15)  [m89].
// In-place safe: stores depend on a[5] (last gather) via the MFMA chain, so every lane's
// reads complete before any of its writes; waves/blocks own disjoint pixels.
template<int IN_BF16, int OUT_BF16, int DO_POOL>
__global__ __launch_bounds__(256, 3) void convmfma_kernel(
    const void* __restrict__ in_, const ushort* __restrict__ Wf,
    const float* __restrict__ bias, void* __restrict__ out_,
    float* __restrict__ px) {
    const int p0 = blockIdx.x * 64;
    const int b = blockIdx.y;
    const int tid = threadIdx.x;
    const int l = tid & 63, w = tid >> 6;
    const size_t plane = (size_t)CDIM * HWP;
    const int pA = p0 + w * 16 + (l & 15);
    const int g8 = (l >> 4) * 8;

    bf16x8 a[6];
    if (IN_BF16) {
        const ushort* inb = (const ushort*)in_ + (size_t)b * plane + pA;
#pragma unroll
        for (int ks = 0; ks < 6; ++ks) {
#pragma unroll
            for (int i = 0; i < 8; ++i)
                a[ks][i] = (short)inb[(size_t)(ks * 32 + g8 + i) * HWP];
        }
    } else {
        const float* inb = (const float*)in_ + (size_t)b * plane + pA;
        float af[6][8];
#pragma unroll
        for (int ks = 0; ks < 6; ++ks)
#pragma unroll
            for (int i = 0; i < 8; ++i)
                af[ks][i] = inb[(size_t)(ks * 32 + g8 + i) * HWP];
        if (DO_POOL) {
            // pool partial: sum this wave's 16 pixels for each c; lanes sharing g8 differ only in pixel
#pragma unroll
            for (int ks = 0; ks < 6; ++ks)
#pragma unroll
                for (int i = 0; i < 8; ++i) {
                    float s = af[ks][i];
                    s += __shfl_xor(s, 1, 64);
                    s += __shfl_xor(s, 2, 64);
                    s += __shfl_xor(s, 4, 64);
                    s += __shfl_xor(s, 8, 64);
                    if ((l & 15) == 0)
                        atomicAdd(&px[(b * CDIM + ks * 32 + g8 + i) * 9 + (p0 >> 10)], s);
                }
        }
#pragma unroll
        for (int ks = 0; ks < 6; ++ks)
#pragma unroll
            for (int i = 0; i < 8; ++i) a[ks][i] = (short)f2bf(af[ks][i]);
    }

    f32x4 acc[12];
#pragma unroll
    for (int nf = 0; nf < 12; ++nf) {
        float bv = bias[nf * 16 + (l & 15)];
        acc[nf] = (f32x4){bv, bv, bv, bv};
    }

#pragma unroll
    for (int ks = 0; ks < 6; ++ks) {
#pragma unroll
        for (int nf = 0; nf < 12; ++nf) {
            bf16x8 bb = *(const bf16x8*)&Wf[(size_t)((ks * 12 + nf) * 64 + l) * 8];
            acc[nf] = __builtin_amdgcn_mfma_f32_16x16x32_bf16(a[ks], bb, acc[nf], 0, 0, 0);
        }
    }

    const int p_out = p0 + w * 16 + (l >> 4) * 4;   // 4 consecutive pixels per lane
#pragma unroll
    for (int nf = 0; nf < 12; ++nf) {
        int o = nf * 16 + (l & 15);
        if (OUT_BF16) {
            ushort* ob = (ushort*)out_ + (size_t)b * plane + (size_t)o * HWP + p_out;
            *(ushort4*)ob = make_ushort4(f2bf(acc[nf][0]), f2bf(acc[nf][1]),
                                         f2bf(acc[nf][2]), f2bf(acc[nf][3]));
        } else {
            float* ob = (float*)out_ + (size_t)b * plane + (size_t)o * HWP + p_out;
            *(float4*)ob = make_float4(acc[nf][0], acc[nf][1], acc[nf][2], acc[nf][3]);
        }
    }
}

// ---------------- small: build per-(b,c) 3x3 kernels (px holds SUMS of 1024 px) ----------------
// Wk staged in LDS chunks (coalesced); read pattern (o+cc) mod 32 -> 2-way (free).
__global__ void make_kernels_kernel(const float* __restrict__ px,
                                    const float* __restrict__ Wk, const float* __restrict__ bk,
                                    const float* __restrict__ Wg, const float* __restrict__ bg,
                                    const float* __restrict__ dc,
                                    float* __restrict__ kk) {
    int b = blockIdx.x;
    int o = threadIdx.x;  // 0..191
    __shared__ float pxs[CDIM * 9];
    __shared__ float WkS[CDIM][33];
    for (int i = threadIdx.x; i < CDIM * 9; i += CDIM)
        pxs[i] = px[b * CDIM * 9 + i] * (1.0f / 1024.0f);
    float k1[9];
    float bias = bk[o];
#pragma unroll
    for (int j = 0; j < 9; j++) k1[j] = bias;

    for (int c0 = 0; c0 < CDIM; c0 += 32) {
        __syncthreads();
        for (int i = threadIdx.x; i < CDIM * 32; i += CDIM) {
            int oo = i >> 5, cc = i & 31;
            WkS[oo][cc] = Wk[oo * CDIM + c0 + cc];
        }
        __syncthreads();
#pragma unroll 4
        for (int cc = 0; cc < 32; ++cc) {
            float wv = WkS[o][cc];
#pragma unroll
            for (int j = 0; j < 9; j++) k1[j] = fmaf(wv, pxs[(c0 + cc) * 9 + j], k1[j]);
        }
    }
#pragma unroll
    for (int j = 0; j < 9; j++) {
        float v = k1[j];
        k1[j] = 0.5f * v * (1.0f + erff(v * 0.70710678118654752f));  // exact GELU
    }
    float k2[9];
    float mean = 0.f;
#pragma unroll
    for (int i = 0; i < 9; i++) {
        float a = bg[i];
#pragma unroll
        for (int j = 0; j < 9; j++) a = fmaf(k1[j], Wg[i * 9 + j], a);
        k2[i] = a;
        mean += a;
    }
    mean *= (1.0f / 9.0f);
    float f = 1.0f / (1.0f + expf(-dc[o]));
    float sub = f * mean;
#pragma unroll
    for (int i = 0; i < 9; i++) kk[(b * CDIM + o) * 9 + i] = k2[i] - sub;
}

// ---------------- depthwise 3x3 via LDS half-image tiles (bf16 in, bf16/f32 out) ----------------
#define SROW 100
template<int OUT_BF16>
__global__ __launch_bounds__(256) void dwconv_kernel_bf16(const ushort* __restrict__ xp,
                                                          const float* __restrict__ kk,
                                                          void* __restrict__ y_) {
    int bc = blockIdx.x >> 1;
    int row0 = (blockIdx.x & 1) * 48;
    int tid = threadIdx.x;

    __shared__ __align__(16) float Sbuf[4 + 50 * SROW + 4];
    float* S = Sbuf + 4;

    float kv[9];
#pragma unroll
    for (int j = 0; j < 9; j++) kv[j] = kk[bc * 9 + j];

    float4 z4 = make_float4(0.f, 0.f, 0.f, 0.f);
    for (int i = tid; i < (4 + 50 * SROW + 4) / 4; i += 256) ((float4*)Sbuf)[i] = z4;
    __syncthreads();

    const ushort* src = xp + (size_t)bc * HWP;
    for (int i = tid; i < 50 * 24; i += 256) {
        int s = i / 24, j4 = i % 24;
        int hh = row0 - 1 + s;
        if (hh >= 0 && hh < HIMG) {
            ushort4 v = *(const ushort4*)(src + (size_t)hh * WIMG + 4 * j4);
            *(float4*)&S[s * SROW + 4 * j4] =
                make_float4(bf2f(v.x), bf2f(v.y), bf2f(v.z), bf2f(v.w));
        }
    }
    __syncthreads();

    for (int i = tid; i < 48 * 24; i += 256) {
        int h = i / 24, wg = i % 24;
        float a0 = 0.f, a1 = 0.f, a2 = 0.f, a3 = 0.f;
#pragma unroll
        for (int r = 0; r < 3; r++) {
            const float* row = &S[(h + r) * SROW + 4 * wg];
            float left = row[-1];
            float4 m = *(const float4*)row;
            float r4 = row[4];
            float c0 = kv[r * 3 + 0], c1 = kv[r * 3 + 1], c2 = kv[r * 3 + 2];
            a0 = fmaf(c0, left, fmaf(c1, m.x, fmaf(c2, m.y, a0)));
            a1 = fmaf(c0, m.x, fmaf(c1, m.y, fmaf(c2, m.z, a1)));
            a2 = fmaf(c0, m.y, fmaf(c1, m.z, fmaf(c2, m.w, a2)));
            a3 = fmaf(c0, m.z, fmaf(c1, m.w, fmaf(c2, r4, a3)));
        }
        if (OUT_BF16) {
            ushort* dst = (ushort*)y_ + (size_t)bc * HWP;
            *(ushort4*)(dst + (size_t)(row0 + h) * WIMG + 4 * wg) =
                make_ushort4(f2bf(a0), f2bf(a1), f2bf(a2), f2bf(a3));
        } else {
            float* dst = (float*)y_ + (size_t)bc * HWP;
            *(float4*)(dst + (size_t)(row0 + h) * WIMG + 4 * wg) =
                make_float4(a0, a1, a2, a3);
        }
    }
}

extern "C" void kernel_launch(void* const* d_in, const int* in_sizes, int n_in,
                              void* d_out, int out_size, void* d_ws, size_t ws_size,
                              hipStream_t stream) {
    const float* x  = (const float*)d_in[0];
    const float* Wk = (const float*)d_in[1];
    const float* bk = (const float*)d_in[2];
    const float* Wg = (const float*)d_in[3];
    const float* bg = (const float*)d_in[4];
    const float* Wx = (const float*)d_in[5];
    const float* bx = (const float*)d_in[6];
    const float* Wp = (const float*)d_in[7];
    const float* bp = (const float*)d_in[8];
    const float* dc = (const float*)d_in[9];
    float* out = (float*)d_out;

    char* ws = (char*)d_ws;
    size_t off_WxF = 0;                           // 36864 bf16
    size_t off_WpF = off_WxF + 36864 * 2;
    size_t off_px  = off_WpF + 36864 * 2;         // 27648 f32 (pool SUMS)
    size_t off_kk  = off_px + 27648 * 4;          // 27648 f32
    size_t off_xp  = off_kk + 27648 * 4;          // B*C*HWP bf16
    size_t xp_bytes = (size_t)BDIM * CDIM * HWP * 2;
    size_t off_y   = off_xp + xp_bytes;

    ushort* WxF = (ushort*)(ws + off_WxF);
    ushort* WpF = (ushort*)(ws + off_WpF);
    float*  px  = (float*)(ws + off_px);
    float*  kkp = (float*)(ws + off_kk);
    ushort* xp  = (ushort*)(ws + off_xp);
    bool y_in_ws = (ws_size >= off_y + xp_bytes);

    hipMemsetAsync(px, 0, 27648 * 4, stream);
    prep_wfrag_kernel<<<dim3(36), dim3(256), 0, stream>>>(Wx, Wp, WxF, WpF);
    // conv1: fp32 in, bf16 out, fused pool partial sums
    convmfma_kernel<0, 1, 1><<<dim3(HWP / 64, BDIM), dim3(256), 0, stream>>>(
        (const void*)x, WxF, bx, (void*)xp, px);
    make_kernels_kernel<<<dim3(BDIM), dim3(CDIM), 0, stream>>>(px, Wk, bk, Wg, bg, dc, kkp);

    if (y_in_ws) {
        ushort* y = (ushort*)(ws + off_y);
        dwconv_kernel_bf16<1><<<dim3(BDIM * CDIM * 2), dim3(256), 0, stream>>>(xp, kkp, (void*)y);
        convmfma_kernel<1, 0, 0><<<dim3(HWP / 64, BDIM), dim3(256), 0, stream>>>(
            (const void*)y, WpF, bp, (void*)out, nullptr);
    } else {
        // fallback: y fp32 in d_out, conv2 in-place
        dwconv_kernel_bf16<0><<<dim3(BDIM * CDIM * 2), dim3(256), 0, stream>>>(xp, kkp, (void*)out);
        convmfma_kernel<0, 0, 0><<<dim3(HWP / 64, BDIM), dim3(256), 0, stream>>>(
            (const void*)out, WpF, bp, (void*)out, nullptr);
    }
}

// Round 7
// 351.281 us; speedup vs baseline: 1.2821x; 1.2821x over previous
//
#include <hip/hip_runtime.h>
#include <math.h>

#define CDIM 192
#define HWP 9216      // 96*96
#define WIMG 96
#define HIMG 96
#define BDIM 16

typedef float f32x4 __attribute__((ext_vector_type(4)));
typedef short bf16x8 __attribute__((ext_vector_type(8)));

__device__ __forceinline__ ushort f2bf(float f) {
    uint u = __builtin_bit_cast(uint, f);
    u += 0x7FFFu + ((u >> 16) & 1);           // round-to-nearest-even
    return (ushort)(u >> 16);
}
__device__ __forceinline__ float bf2f(ushort h) {
    return __builtin_bit_cast(float, (uint)h << 16);
}

// Swizzled LDS index (ushort units). Row pitch 256 ushort = 512 B.
// XOR value (((p>>2)^p)&7)<<3 spreads the 4-row-stride transpose writes AND the
// 16-consecutive-row b128 reads to <=2 lanes/bank (free per m136).
__device__ __forceinline__ int sidx(int p, int c) {
    return (p << 8) + (c ^ ((((p >> 2) ^ p) & 7) << 3));
}

// ---------------- prep: bake W (o-major [192][192] fp32) into MFMA B-fragment order ----------------
// Wf[((ks*12 + nf)*64 + l)*8 + i] = bf16( W[o=nf*16+(l&15)][c = ks*32 + (l>>4)*8 + i] )
// The (g,i)->k mapping is applied identically on the A-side (contiguous c per lane), so it cancels.
__global__ void prep_wfrag_kernel(const float* __restrict__ Wx, const float* __restrict__ Wp,
                                  ushort* __restrict__ WxF, ushort* __restrict__ WpF) {
    int t = blockIdx.x * 256 + threadIdx.x;    // 0 .. 9215
    int m = t / 4608;
    int r = t % 4608;                          // ks*768 + nf*64 + l
    int ks = r / 768, nf = (r / 64) % 12, l = r % 64;
    const float* W = m ? Wp : Wx;
    ushort* F = m ? WpF : WxF;
    int o = nf * 16 + (l & 15);
    int c0 = ks * 32 + (l >> 4) * 8;
    float4 a = *(const float4*)&W[o * CDIM + c0];
    float4 b = *(const float4*)&W[o * CDIM + c0 + 4];
    ushort* dst = F + (size_t)r * 8;
    dst[0] = f2bf(a.x); dst[1] = f2bf(a.y); dst[2] = f2bf(a.z); dst[3] = f2bf(a.w);
    dst[4] = f2bf(b.x); dst[5] = f2bf(b.y); dst[6] = f2bf(b.z); dst[7] = f2bf(b.w);
}

// ---------------- conv1: x [b][c][p] fp32 -> xp [b][p][c] bf16, fused pool sums ----------------
// Block = 64 pixels x all 192 out-ch; 4 waves, wave w owns pixels [p0+16w,+16).
// Stage+transpose x-tile into swizzled S[p][c] bf16; A-frag = one ds_read_b128.
// D layout: row=pixel=(l>>4)*4+reg, col=o=l&15 [m89]. Result goes back through S
// (swizzled scalar writes, ~2-way) and is read out as [p][c]-contiguous 16 B stores.
__global__ __launch_bounds__(256, 2) void conv1_kernel(
    const float* __restrict__ x, const ushort* __restrict__ Wf,
    const float* __restrict__ bias, ushort* __restrict__ xp,
    float* __restrict__ px) {
    const int p0 = blockIdx.x * 64;
    const int b = blockIdx.y;
    const int tid = threadIdx.x;
    const int l = tid & 63, w = tid >> 6;

    __shared__ __align__(16) ushort S[64 * 256];   // 32 KB, swizzled

    const float* inb = x + (size_t)b * CDIM * HWP;
#pragma unroll
    for (int it = 0; it < 3; ++it) {
        int u = tid + it * 256;                // 768 4x4 sub-blocks
        int p4 = (u & 15) * 4, c4 = (u >> 4) * 4;
        ushort vv[4][4];
#pragma unroll
        for (int r = 0; r < 4; ++r) {
            float4 t4 = *(const float4*)(inb + (size_t)(c4 + r) * HWP + p0 + p4);
            vv[r][0] = f2bf(t4.x); vv[r][1] = f2bf(t4.y);
            vv[r][2] = f2bf(t4.z); vv[r][3] = f2bf(t4.w);
        }
#pragma unroll
        for (int q = 0; q < 4; ++q)
            *(ushort4*)&S[sidx(p4 + q, c4)] =
                make_ushort4(vv[0][q], vv[1][q], vv[2][q], vv[3][q]);
    }
    __syncthreads();

    // pool partial sums over this block's 64 pixels (segment p0/1024)
    if (tid < CDIM) {
        float s = 0.f;
#pragma unroll 8
        for (int p = 0; p < 64; ++p) s += bf2f(S[sidx(p, tid)]);
        atomicAdd(&px[(b * CDIM + tid) * 9 + (p0 >> 10)], s);
    }

    f32x4 acc[12];
#pragma unroll
    for (int nf = 0; nf < 12; ++nf) {
        float bv = bias[nf * 16 + (l & 15)];
        acc[nf] = (f32x4){bv, bv, bv, bv};
    }

    const int g8 = (l >> 4) * 8;
    const int prow = w * 16 + (l & 15);
#pragma unroll
    for (int ks = 0; ks < 6; ++ks) {
        bf16x8 a = *(const bf16x8*)&S[sidx(prow, ks * 32 + g8)];
#pragma unroll
        for (int nf = 0; nf < 12; ++nf) {
            bf16x8 bb = *(const bf16x8*)&Wf[(size_t)((ks * 12 + nf) * 64 + l) * 8];
            acc[nf] = __builtin_amdgcn_mfma_f32_16x16x32_bf16(a, bb, acc[nf], 0, 0, 0);
        }
    }
    __syncthreads();   // A-reads + pool reads done before S is overwritten

    const int pw = w * 16 + (l >> 4) * 4;
#pragma unroll
    for (int nf = 0; nf < 12; ++nf) {
        int o = nf * 16 + (l & 15);
#pragma unroll
        for (int q = 0; q < 4; ++q) S[sidx(pw + q, o)] = f2bf(acc[nf][q]);
    }
    __syncthreads();

    // coalesced readout: xp[b][p0+r][c]
    ushort* ob = xp + ((size_t)b * HWP + p0) * CDIM;
#pragma unroll
    for (int it = 0; it < 6; ++it) {
        int u = tid + it * 256;                // 1536 = 64 rows x 24 cgroups
        int r = u / 24, cg = u % 24;
        *(bf16x8*)(ob + (size_t)r * CDIM + cg * 8) = *(const bf16x8*)&S[sidx(r, cg * 8)];
    }
}

// ---------------- conv2: y [b][p][c] bf16 -> out [b][o][p] fp32 (pure streaming, no LDS) ----------------
// A-frag = one contiguous bf16x8 global load per lane per ks (wave: 16 rows x 64 B full lines).
__global__ __launch_bounds__(256, 3) void conv2_kernel(
    const ushort* __restrict__ y, const ushort* __restrict__ Wf,
    const float* __restrict__ bias, float* __restrict__ out) {
    const int p0 = blockIdx.x * 64;
    const int b = blockIdx.y;
    const int l = threadIdx.x & 63, w = threadIdx.x >> 6;
    const int g8 = (l >> 4) * 8;
    const int pA = p0 + w * 16 + (l & 15);

    const ushort* yb = y + ((size_t)b * HWP + pA) * CDIM + g8;
    bf16x8 a[6];
#pragma unroll
    for (int ks = 0; ks < 6; ++ks) a[ks] = *(const bf16x8*)(yb + ks * 32);

    f32x4 acc[12];
#pragma unroll
    for (int nf = 0; nf < 12; ++nf) {
        float bv = bias[nf * 16 + (l & 15)];
        acc[nf] = (f32x4){bv, bv, bv, bv};
    }
#pragma unroll
    for (int ks = 0; ks < 6; ++ks) {
#pragma unroll
        for (int nf = 0; nf < 12; ++nf) {
            bf16x8 bb = *(const bf16x8*)&Wf[(size_t)((ks * 12 + nf) * 64 + l) * 8];
            acc[nf] = __builtin_amdgcn_mfma_f32_16x16x32_bf16(a[ks], bb, acc[nf], 0, 0, 0);
        }
    }

    const int p_out = p0 + w * 16 + (l >> 4) * 4;
    float* ob = out + (size_t)b * CDIM * HWP + p_out;
#pragma unroll
    for (int nf = 0; nf < 12; ++nf) {
        int o = nf * 16 + (l & 15);
        *(float4*)(ob + (size_t)o * HWP) =
            make_float4(acc[nf][0], acc[nf][1], acc[nf][2], acc[nf][3]);
    }
}

// ---------------- small: build per-(b,c) 3x3 kernels; output TRANSPOSED kkT[b][j][c] ----------------
__global__ void make_kernels_kernel(const float* __restrict__ px,
                                    const float* __restrict__ Wk, const float* __restrict__ bk,
                                    const float* __restrict__ Wg, const float* __restrict__ bg,
                                    const float* __restrict__ dc,
                                    float* __restrict__ kkT) {
    int b = blockIdx.x;
    int o = threadIdx.x;  // 0..191
    __shared__ float pxs[CDIM * 9];
    __shared__ float WkS[CDIM][33];
    for (int i = threadIdx.x; i < CDIM * 9; i += CDIM)
        pxs[i] = px[b * CDIM * 9 + i] * (1.0f / 1024.0f);
    float k1[9];
    float bias = bk[o];
#pragma unroll
    for (int j = 0; j < 9; j++) k1[j] = bias;

    for (int c0 = 0; c0 < CDIM; c0 += 32) {
        __syncthreads();
        for (int i = threadIdx.x; i < CDIM * 32; i += CDIM) {
            int oo = i >> 5, cc = i & 31;
            WkS[oo][cc] = Wk[oo * CDIM + c0 + cc];
        }
        __syncthreads();
#pragma unroll 4
        for (int cc = 0; cc < 32; ++cc) {
            float wv = WkS[o][cc];
#pragma unroll
            for (int j = 0; j < 9; j++) k1[j] = fmaf(wv, pxs[(c0 + cc) * 9 + j], k1[j]);
        }
    }
#pragma unroll
    for (int j = 0; j < 9; j++) {
        float v = k1[j];
        k1[j] = 0.5f * v * (1.0f + erff(v * 0.70710678118654752f));  // exact GELU
    }
    float k2[9];
    float mean = 0.f;
#pragma unroll
    for (int i = 0; i < 9; i++) {
        float a = bg[i];
#pragma unroll
        for (int j = 0; j < 9; j++) a = fmaf(k1[j], Wg[i * 9 + j], a);
        k2[i] = a;
        mean += a;
    }
    mean *= (1.0f / 9.0f);
    float f = 1.0f / (1.0f + expf(-dc[o]));
    float sub = f * mean;
#pragma unroll
    for (int i = 0; i < 9; i++) kkT[(b * 9 + i) * CDIM + o] = k2[i] - sub;
}

// ---------------- depthwise 3x3, channel-last: xp/y [b][p][c] bf16 ----------------
// Thread = (pixel, 8-channel group): 9 neighbor bf16x8 loads + 9x2 float4 kernel loads.
__global__ __launch_bounds__(256) void dwconv_cl_kernel(const ushort* __restrict__ xp,
                                                        const float* __restrict__ kkT,
                                                        ushort* __restrict__ y) {
    int idx = blockIdx.x * 256 + threadIdx.x;
    int cg = idx % 24;
    int pb = idx / 24;                 // b*HWP + p
    int p = pb % HWP, b = pb / HWP;
    int h = p / WIMG, wq = p % WIMG;

    const ushort* base = xp + (size_t)pb * CDIM + cg * 8;
    const float* kb = kkT + (size_t)b * 9 * CDIM + cg * 8;

    float acc[8];
#pragma unroll
    for (int i = 0; i < 8; ++i) acc[i] = 0.f;

#pragma unroll
    for (int dh = -1; dh <= 1; ++dh) {
        int hh = h + dh;
        if (hh < 0 || hh >= HIMG) continue;
#pragma unroll
        for (int dw = -1; dw <= 1; ++dw) {
            int ww = wq + dw;
            if (ww < 0 || ww >= WIMG) continue;
            int j = (dh + 1) * 3 + (dw + 1);
            bf16x8 v = *(const bf16x8*)(base + (ptrdiff_t)(dh * WIMG + dw) * CDIM);
            float4 k0 = *(const float4*)(kb + j * CDIM);
            float4 k1 = *(const float4*)(kb + j * CDIM + 4);
            acc[0] = fmaf(bf2f((ushort)v[0]), k0.x, acc[0]);
            acc[1] = fmaf(bf2f((ushort)v[1]), k0.y, acc[1]);
            acc[2] = fmaf(bf2f((ushort)v[2]), k0.z, acc[2]);
            acc[3] = fmaf(bf2f((ushort)v[3]), k0.w, acc[3]);
            acc[4] = fmaf(bf2f((ushort)v[4]), k1.x, acc[4]);
            acc[5] = fmaf(bf2f((ushort)v[5]), k1.y, acc[5]);
            acc[6] = fmaf(bf2f((ushort)v[6]), k1.z, acc[6]);
            acc[7] = fmaf(bf2f((ushort)v[7]), k1.w, acc[7]);
        }
    }
    ushort* dst = y + (size_t)pb * CDIM + cg * 8;
    ushort4 o0 = make_ushort4(f2bf(acc[0]), f2bf(acc[1]), f2bf(acc[2]), f2bf(acc[3]));
    ushort4 o1 = make_ushort4(f2bf(acc[4]), f2bf(acc[5]), f2bf(acc[6]), f2bf(acc[7]));
    *(ushort4*)dst = o0;
    *(ushort4*)(dst + 4) = o1;
}

extern "C" void kernel_launch(void* const* d_in, const int* in_sizes, int n_in,
                              void* d_out, int out_size, void* d_ws, size_t ws_size,
                              hipStream_t stream) {
    const float* x  = (const float*)d_in[0];
    const float* Wk = (const float*)d_in[1];
    const float* bk = (const float*)d_in[2];
    const float* Wg = (const float*)d_in[3];
    const float* bg = (const float*)d_in[4];
    const float* Wx = (const float*)d_in[5];
    const float* bx = (const float*)d_in[6];
    const float* Wp = (const float*)d_in[7];
    const float* bp = (const float*)d_in[8];
    const float* dc = (const float*)d_in[9];
    float* out = (float*)d_out;

    char* ws = (char*)d_ws;
    // layout (bytes); total = 113,614,848 <= ws floor 113,762,304 proven in round 2
    size_t off_WxF = 0;                           // 36864 bf16
    size_t off_WpF = off_WxF + 36864 * 2;
    size_t off_px  = off_WpF + 36864 * 2;         // 27648 f32 (pool SUMS)
    size_t off_kk  = off_px + 27648 * 4;          // 27648 f32 (kkT [b][9][c])
    size_t off_xp  = off_kk + 27648 * 4;          // [b][p][c] bf16
    size_t xp_bytes = (size_t)BDIM * CDIM * HWP * 2;
    size_t off_y   = off_xp + xp_bytes;           // [b][p][c] bf16

    ushort* WxF = (ushort*)(ws + off_WxF);
    ushort* WpF = (ushort*)(ws + off_WpF);
    float*  px  = (float*)(ws + off_px);
    float*  kkT = (float*)(ws + off_kk);
    ushort* xp  = (ushort*)(ws + off_xp);
    ushort* y   = (ushort*)(ws + off_y);

    hipMemsetAsync(px, 0, 27648 * 4, stream);
    prep_wfrag_kernel<<<dim3(36), dim3(256), 0, stream>>>(Wx, Wp, WxF, WpF);
    conv1_kernel<<<dim3(HWP / 64, BDIM), dim3(256), 0, stream>>>(x, WxF, bx, xp, px);
    make_kernels_kernel<<<dim3(BDIM), dim3(CDIM), 0, stream>>>(px, Wk, bk, Wg, bg, dc, kkT);
    dwconv_cl_kernel<<<dim3((size_t)BDIM * HWP * 24 / 256), dim3(256), 0, stream>>>(xp, kkT, y);
    conv2_kernel<<<dim3(HWP / 64, BDIM), dim3(256), 0, stream>>>(y, WpF, bp, out);
}